// Round 7
// baseline (710.946 us; speedup 1.0000x reference)
//
#include <hip/hip_runtime.h>

// GCN forward: 2× (GCNConv) + mean-pool + linear head, f32.
//   count in-deg -> dinv -> exclusive scan -> 2-phase bucketed scatter (CSR by dst)
//   t = (x@W1)*dinv ; agg1: h1 = relu((sum_in t + t[self])*dinv + b1),
//                     fused epilogue: q[v] = dinv[v] * (h1[v] . w2l)   [scalar]
//   agg2 (head collapsed): p[v] = dinv[v]*(sum_in q + q[v]); graph-mean
//   out[g] = mean_g(p) + b2.Wl + bl
//
// R2: edge loop unrolled x8 (best gather config). R3/R5 deeper: REGRESSED.
// R4: bf16 t: bytes halved, time flat -> aggs bound by random-access rate.
// R6: layer-2 collapsed to scalar q table: 785->636 us.
// R7: k_scatter was #1 (128 us, WRITE_SIZE 105 MB = 16x write-allocate
//     inflation from random 4B stores). Two-phase bucket scatter:
//     bucket=dst>>5; bucket region of srt = [rp[32b], rp[32b+32]) (free from
//     scan). Phase A packs (src,dst) into bucket-ordered ebuf (~3125 active
//     tail lines, L2-resident); phase B streams ebuf and stores srt locally.

__global__ void k_count(const int* __restrict__ dst, int* __restrict__ cnt, int E) {
    int e = blockIdx.x * blockDim.x + threadIdx.x;
    if (e < E) atomicAdd(&cnt[dst[e]], 1);
}

__global__ void k_dinv(const int* __restrict__ cnt, float* __restrict__ dinv, int N) {
    int i = blockIdx.x * blockDim.x + threadIdx.x;
    if (i < N) dinv[i] = 1.0f / sqrtf((float)cnt[i] + 1.0f);  // +1 self loop
}

// w2l[i] = sum_j W2[i][j] * Wl[j]
__global__ void k_w2l(const float* __restrict__ W2, const float* __restrict__ Wl,
                      float* __restrict__ w2l) {
    int i = threadIdx.x;   // 128 threads
    float s = 0.0f;
    for (int j = 0; j < 128; ++j) s = fmaf(W2[i * 128 + j], Wl[j], s);
    w2l[i] = s;
}

// Exclusive scan of cnt[N] -> rp[N]; per-chunk totals to bsum.
__global__ void k_scan_a(const int* __restrict__ cnt, int* __restrict__ rp,
                         int* __restrict__ bsum, int N) {
    __shared__ int tmp[1024];
    int i = blockIdx.x * 1024 + threadIdx.x;
    int v = (i < N) ? cnt[i] : 0;
    tmp[threadIdx.x] = v;
    __syncthreads();
    for (int off = 1; off < 1024; off <<= 1) {
        int t = (threadIdx.x >= off) ? tmp[threadIdx.x - off] : 0;
        __syncthreads();
        tmp[threadIdx.x] += t;
        __syncthreads();
    }
    if (i < N) rp[i] = (threadIdx.x == 0) ? 0 : tmp[threadIdx.x - 1];
    if (threadIdx.x == 1023) bsum[blockIdx.x] = tmp[1023];
}

// Exclusive scan of chunk totals (nb <= 128).
__global__ void k_scan_b(int* __restrict__ bsum, int nb) {
    __shared__ int tmp[128];
    int t = threadIdx.x;
    int v = (t < nb) ? bsum[t] : 0;
    tmp[t] = v;
    __syncthreads();
    for (int off = 1; off < 128; off <<= 1) {
        int u = (t >= off) ? tmp[t - off] : 0;
        __syncthreads();
        tmp[t] += u;
        __syncthreads();
    }
    if (t < nb) bsum[t] = (t == 0) ? 0 : tmp[t - 1];
}

// rp/cur finalize + bucket tails bcur[b] = rp[min(32b,N)].
__global__ void k_scan_c(int* __restrict__ rp, const int* __restrict__ bsum,
                         int* __restrict__ cur, int* __restrict__ bcur,
                         int N, int E, int NBUK) {
    int i = blockIdx.x * blockDim.x + threadIdx.x;
    int v = 0;
    if (i <= N) {
        v = (i < N) ? rp[i] + bsum[i >> 10] : E;
        if (i < N) { rp[i] = v; cur[i] = v; }
        else rp[N] = E;
    }
    if (i <= N && (i & 31) == 0) {
        int b = i >> 5;
        if (b <= NBUK) bcur[b] = v;
    }
    if (i == N && (N & 31) != 0) bcur[NBUK] = E;   // tail guard (unused)
}

// Phase A: pack (src,dst) into bucket-major ebuf. Active write tails =
// NBUK lines (L2-resident) -> near-full-line writebacks.
__global__ void k_bucket(const int* __restrict__ src, const int* __restrict__ dst,
                         int* __restrict__ bcur,
                         unsigned long long* __restrict__ ebuf, int E) {
    int e = blockIdx.x * blockDim.x + threadIdx.x;
    if (e < E) {
        int d = dst[e];
        int b = d >> 5;
        int pos = atomicAdd(&bcur[b], 1);
        ebuf[pos] = (unsigned)src[e] | ((unsigned long long)(unsigned)d << 32);
    }
}

// Phase B: stream ebuf (coalesced); same-bucket edges are adjacent, so the
// srt stores land in a ~2KB contiguous region -> full-line writebacks.
__global__ void k_scatter2(const unsigned long long* __restrict__ ebuf,
                           int* __restrict__ cur, int* __restrict__ srt, int E) {
    int e = blockIdx.x * blockDim.x + threadIdx.x;
    if (e < E) {
        unsigned long long w = ebuf[e];
        int s = (int)(unsigned)w;
        int d = (int)(unsigned)(w >> 32);
        int pos = atomicAdd(&cur[d], 1);
        srt[pos] = s;
    }
}

// C[r][:] = (A[r][:] @ B) * dinv[r];  A: N x 128, B: 128 x 128 row-major.
// Classic 128x128 block, 8x8 per thread, BK=8.
__global__ __launch_bounds__(256) void k_mm_scale(
    const float* __restrict__ A, const float* __restrict__ B,
    const float* __restrict__ dinv, float* __restrict__ C, int N)
{
    __shared__ float As[8][128];   // [k][m] (transposed store)
    __shared__ float Bs[8][128];   // [k][n]
    int tid = threadIdx.x;
    int row0 = blockIdx.x * 128;
    int a_row = tid >> 1;            // 0..127
    int a_col = (tid & 1) * 4;       // 0 or 4
    int b_row = tid >> 5;            // 0..7
    int b_col = (tid & 31) * 4;      // 0..124
    int tx = tid & 15;               // col group (8 cols each)
    int ty = tid >> 4;               // row group (8 rows each)

    float acc[8][8];
#pragma unroll
    for (int i = 0; i < 8; ++i)
#pragma unroll
        for (int j = 0; j < 8; ++j) acc[i][j] = 0.0f;

    for (int k0 = 0; k0 < 128; k0 += 8) {
        int gr = row0 + a_row;
        if (gr > N - 1) gr = N - 1;   // clamp: OOB rows discarded at store
        float4 av = *(const float4*)(A + (size_t)gr * 128 + k0 + a_col);
        float4 bv = *(const float4*)(B + (size_t)(k0 + b_row) * 128 + b_col);
        As[a_col + 0][a_row] = av.x;
        As[a_col + 1][a_row] = av.y;
        As[a_col + 2][a_row] = av.z;
        As[a_col + 3][a_row] = av.w;
        *(float4*)&Bs[b_row][b_col] = bv;
        __syncthreads();
#pragma unroll
        for (int kk = 0; kk < 8; ++kk) {
            float a[8], b[8];
#pragma unroll
            for (int i = 0; i < 8; ++i) a[i] = As[kk][ty * 8 + i];
#pragma unroll
            for (int j = 0; j < 8; ++j) b[j] = Bs[kk][tx * 8 + j];
#pragma unroll
            for (int i = 0; i < 8; ++i)
#pragma unroll
                for (int j = 0; j < 8; ++j)
                    acc[i][j] = fmaf(a[i], b[j], acc[i][j]);
        }
        __syncthreads();
    }

#pragma unroll
    for (int i = 0; i < 8; ++i) {
        int r = row0 + ty * 8 + i;
        if (r < N) {
            float s = dinv[r];
            float4 o0 = {acc[i][0] * s, acc[i][1] * s, acc[i][2] * s, acc[i][3] * s};
            float4 o1 = {acc[i][4] * s, acc[i][5] * s, acc[i][6] * s, acc[i][7] * s};
            *(float4*)(C + (size_t)r * 128 + tx * 8) = o0;
            *(float4*)(C + (size_t)r * 128 + tx * 8 + 4) = o1;
        }
    }
}

// Edge accumulation with 8 gathers in flight (R2 best config): sum over
// in-edges (pre-scaled rows) + self row, float2 per lane.
__device__ __forceinline__ float2 edge_accum(
    const float* __restrict__ t, const int* __restrict__ srt,
    int s0, int s1, int node, int lane)
{
    float2 a0 = {0,0}, a1 = {0,0}, a2 = {0,0}, a3 = {0,0};
    int e = s0;
    int fo = lane * 2;
    while (e + 8 <= s1) {
        int idx[8];
#pragma unroll
        for (int j = 0; j < 8; ++j) idx[j] = srt[e + j];
        float2 v[8];
#pragma unroll
        for (int j = 0; j < 8; ++j)
            v[j] = *(const float2*)(t + (size_t)idx[j] * 128 + fo);
        a0.x += v[0].x; a0.y += v[0].y;  a1.x += v[1].x; a1.y += v[1].y;
        a2.x += v[2].x; a2.y += v[2].y;  a3.x += v[3].x; a3.y += v[3].y;
        a0.x += v[4].x; a0.y += v[4].y;  a1.x += v[5].x; a1.y += v[5].y;
        a2.x += v[6].x; a2.y += v[6].y;  a3.x += v[7].x; a3.y += v[7].y;
        e += 8;
    }
    if (e + 4 <= s1) {
        int idx[4];
#pragma unroll
        for (int j = 0; j < 4; ++j) idx[j] = srt[e + j];
        float2 v[4];
#pragma unroll
        for (int j = 0; j < 4; ++j)
            v[j] = *(const float2*)(t + (size_t)idx[j] * 128 + fo);
        a0.x += v[0].x; a0.y += v[0].y;  a1.x += v[1].x; a1.y += v[1].y;
        a2.x += v[2].x; a2.y += v[2].y;  a3.x += v[3].x; a3.y += v[3].y;
        e += 4;
    }
    for (; e < s1; ++e) {
        int s = srt[e];
        float2 v = *(const float2*)(t + (size_t)s * 128 + fo);
        a0.x += v.x; a0.y += v.y;
    }
    float2 vs = *(const float2*)(t + (size_t)node * 128 + fo);  // self loop
    float2 acc;
    acc.x = (a0.x + a1.x) + (a2.x + a3.x) + vs.x;
    acc.y = (a0.y + a1.y) + (a2.y + a3.y) + vs.y;
    return acc;
}

// One wave per node: h1 = relu((sum_in t + t[self])*dinv + b1), then the
// collapsed layer-2 projection q[node] = dinv * (h1 . w2l). Only q is stored.
__global__ __launch_bounds__(256) void k_agg1(
    const float* __restrict__ t, const float* __restrict__ dinv,
    const int* __restrict__ rp, const int* __restrict__ srt,
    const float* __restrict__ b1, const float* __restrict__ w2l,
    float* __restrict__ q, int N)
{
    int wave = threadIdx.x >> 6;
    int lane = threadIdx.x & 63;
    int node = blockIdx.x * 4 + wave;
    if (node >= N) return;
    int s0 = rp[node], s1 = rp[node + 1];
    float2 acc = edge_accum(t, srt, s0, s1, node, lane);
    float di = dinv[node];
    float2 bb = *(const float2*)(b1 + lane * 2);
    float2 ww = *(const float2*)(w2l + lane * 2);
    float hx = fmaxf(fmaf(acc.x, di, bb.x), 0.0f);
    float hy = fmaxf(fmaf(acc.y, di, bb.y), 0.0f);
    float p = hx * ww.x + hy * ww.y;
#pragma unroll
    for (int off = 32; off > 0; off >>= 1) p += __shfl_down(p, off);
    if (lane == 0) q[node] = p * di;
}

// Collapsed layer-2 aggregation + pooling: one THREAD per node over the
// scalar q table (400 KB, L2-resident). p[v] = dinv[v]*(sum_in q + q[v]).
__global__ __launch_bounds__(256) void k_agg2(
    const float* __restrict__ q, const float* __restrict__ dinv,
    const int* __restrict__ rp, const int* __restrict__ srt,
    const int* __restrict__ batch, float* __restrict__ gsum,
    int* __restrict__ gcnt, int N)
{
    int i = blockIdx.x * blockDim.x + threadIdx.x;
    if (i >= N) return;
    int s0 = rp[i], s1 = rp[i + 1];
    float a0 = 0.0f, a1 = 0.0f, a2 = 0.0f, a3 = 0.0f;
    int e = s0;
    for (; e + 4 <= s1; e += 4) {
        a0 += q[srt[e]];
        a1 += q[srt[e + 1]];
        a2 += q[srt[e + 2]];
        a3 += q[srt[e + 3]];
    }
    for (; e < s1; ++e) a0 += q[srt[e]];
    float p = dinv[i] * ((a0 + a1) + (a2 + a3) + q[i]);
    atomicAdd(&gsum[batch[i]], p);
    atomicAdd(&gcnt[batch[i]], 1);
}

// out[g] = gsum/cnt + b2.Wl + bl   (b2.Wl constant across nodes/graphs)
__global__ void k_final(const float* __restrict__ gsum, const int* __restrict__ gcnt,
                        const float* __restrict__ b2, const float* __restrict__ Wl,
                        const float* __restrict__ bl, float* __restrict__ out, int G) {
    int g = blockIdx.x * blockDim.x + threadIdx.x;
    if (g < G) {
        float c = 0.0f;
        for (int j = 0; j < 128; ++j) c = fmaf(b2[j], Wl[j], c);
        out[g] = gsum[g] / fmaxf((float)gcnt[g], 1.0f) + c + bl[0];
    }
}

extern "C" void kernel_launch(void* const* d_in, const int* in_sizes, int n_in,
                              void* d_out, int out_size, void* d_ws, size_t ws_size,
                              hipStream_t stream)
{
    const float* x  = (const float*)d_in[0];
    const int*   ei = (const int*)d_in[1];
    // d_in[2] = edge_attr: unused by the reference
    const int*   batch = (const int*)d_in[3];
    const float* W1 = (const float*)d_in[4];
    const float* b1 = (const float*)d_in[5];
    const float* W2 = (const float*)d_in[6];
    const float* b2 = (const float*)d_in[7];
    const float* Wl = (const float*)d_in[8];
    const float* bl = (const float*)d_in[9];

    int N = in_sizes[0] / 128;
    int E = in_sizes[1] / 2;
    const int* src = ei;
    const int* dst = ei + E;
    int NBUK = (N + 31) / 32;

    char* ws = (char*)d_ws;
    size_t off = 0;
    auto alloc = [&](size_t bytes) -> void* {
        void* p = ws + off;
        off = (off + bytes + 255) & ~(size_t)255;
        return p;
    };
    float* t    = (float*)alloc((size_t)N * 128 * 4);   // (x@W1)*dinv, f32
    unsigned long long* ebuf = (unsigned long long*)alloc((size_t)E * 8);
    float* q    = (float*)alloc((size_t)N * 4);         // collapsed layer-2 scalars
    int*   srt  = (int*)alloc((size_t)E * 4);
    int*   cnt  = (int*)alloc((size_t)N * 4);
    float* dinv = (float*)alloc((size_t)N * 4);
    int*   rp   = (int*)alloc((size_t)(N + 1) * 4);
    int*   cur  = (int*)alloc((size_t)N * 4);
    int*   bcur = (int*)alloc((size_t)(NBUK + 1) * 4);
    int*   bsum = (int*)alloc(1024 * 4);
    float* gsum = (float*)alloc(512 * 4);
    int*   gcnt = (int*)alloc(512 * 4);
    float* w2l  = (float*)alloc(128 * 4);
    (void)ws_size;

    hipMemsetAsync(cnt, 0, (size_t)N * 4, stream);
    hipMemsetAsync(gsum, 0, 512 * 4, stream);
    hipMemsetAsync(gcnt, 0, 512 * 4, stream);

    int eb = (E + 255) / 256;
    int nb = (N + 255) / 256;
    k_count<<<eb, 256, 0, stream>>>(dst, cnt, E);
    k_dinv<<<nb, 256, 0, stream>>>(cnt, dinv, N);
    k_w2l<<<1, 128, 0, stream>>>(W2, Wl, w2l);
    int nchunk = (N + 1023) / 1024;   // 98 <= 128 (k_scan_b capacity)
    k_scan_a<<<nchunk, 1024, 0, stream>>>(cnt, rp, bsum, N);
    k_scan_b<<<1, 128, 0, stream>>>(bsum, nchunk);
    k_scan_c<<<(N + 256) / 256, 256, 0, stream>>>(rp, bsum, cur, bcur, N, E, NBUK);
    k_bucket<<<eb, 256, 0, stream>>>(src, dst, bcur, ebuf, E);
    k_scatter2<<<eb, 256, 0, stream>>>(ebuf, cur, srt, E);

    int mmb = (N + 127) / 128;
    k_mm_scale<<<mmb, 256, 0, stream>>>(x, W1, dinv, t, N);
    k_agg1<<<(N + 3) / 4, 256, 0, stream>>>(t, dinv, rp, srt, b1, w2l, q, N);
    k_agg2<<<nb, 256, 0, stream>>>(q, dinv, rp, srt, batch, gsum, gcnt, N);
    k_final<<<2, 256, 0, stream>>>(gsum, gcnt, b2, Wl, bl, (float*)d_out, 512);
}

// Round 8
// 610.388 us; speedup vs baseline: 1.1647x; 1.1647x over previous
//
#include <hip/hip_runtime.h>

// GCN forward: 2× (GCNConv) + mean-pool + linear head.
//   count in-deg -> dinv -> exclusive scan -> scatter (CSR by dst)
//   t = (x@W1)*dinv  [bf16 MFMA, f32 out]
//   agg1: h1 = relu((sum_in t + t[self])*dinv + b1); q[v] = dinv[v]*(h1.w2l)
//   agg2 (head collapsed): p[v] = dinv[v]*(sum_in q + q[v]); graph-mean
//   out[g] = mean_g(p) + b2.Wl + bl
//
// R2: edge loop unrolled x8 (best gather config). R3/R5 deeper: REGRESSED.
// R4: bf16 t: bytes halved, time flat -> aggs bound by random-access rate.
// R6: layer-2 collapsed to scalar q table: 785->636 us.
// R7: two-phase bucket scatter REGRESSED (+75us): cross-XCD interleaved
//     appends to shared lines never merge (non-coherent L2s) -> same 64B/edge
//     writeback inflation PLUS an extra pass. Reverted to single-phase.
// R8: k_mm_scale (95us @ 35TF f32 VALU) -> bf16 MFMA 16x16x32 (inputs cast
//     to bf16, f32 accumulate/output).

typedef __attribute__((ext_vector_type(8))) short short8;
typedef __attribute__((ext_vector_type(4))) float f32x4;

__device__ __forceinline__ unsigned short bf16r(float f) {
    unsigned u = __float_as_uint(f);
    u += 0x7FFFu + ((u >> 16) & 1u);
    return (unsigned short)(u >> 16);
}

__global__ void k_count(const int* __restrict__ dst, int* __restrict__ cnt, int E) {
    int e = blockIdx.x * blockDim.x + threadIdx.x;
    if (e < E) atomicAdd(&cnt[dst[e]], 1);
}

__global__ void k_dinv(const int* __restrict__ cnt, float* __restrict__ dinv, int N) {
    int i = blockIdx.x * blockDim.x + threadIdx.x;
    if (i < N) dinv[i] = 1.0f / sqrtf((float)cnt[i] + 1.0f);  // +1 self loop
}

// w2l[i] = sum_j W2[i][j] * Wl[j]
__global__ void k_w2l(const float* __restrict__ W2, const float* __restrict__ Wl,
                      float* __restrict__ w2l) {
    int i = threadIdx.x;   // 128 threads
    float s = 0.0f;
    for (int j = 0; j < 128; ++j) s = fmaf(W2[i * 128 + j], Wl[j], s);
    w2l[i] = s;
}

// Pack W1 (128x128 f32, [k][n]) into bf16 chunked layout for MFMA B-frags:
// w1p[ (k>>3)*128*8 + n*8 + (k&7) ]  -> lane reads 8 consecutive k as 16B.
__global__ void k_w1pack(const float* __restrict__ W1, unsigned short* __restrict__ w1p) {
    int idx = blockIdx.x * blockDim.x + threadIdx.x;   // 16384
    if (idx < 16384) {
        int k = idx >> 7, n = idx & 127;
        w1p[((k >> 3) * 128 + n) * 8 + (k & 7)] = bf16r(W1[idx]);
    }
}

// Exclusive scan of cnt[N] -> rp[N]; per-chunk totals to bsum.
__global__ void k_scan_a(const int* __restrict__ cnt, int* __restrict__ rp,
                         int* __restrict__ bsum, int N) {
    __shared__ int tmp[1024];
    int i = blockIdx.x * 1024 + threadIdx.x;
    int v = (i < N) ? cnt[i] : 0;
    tmp[threadIdx.x] = v;
    __syncthreads();
    for (int off = 1; off < 1024; off <<= 1) {
        int t = (threadIdx.x >= off) ? tmp[threadIdx.x - off] : 0;
        __syncthreads();
        tmp[threadIdx.x] += t;
        __syncthreads();
    }
    if (i < N) rp[i] = (threadIdx.x == 0) ? 0 : tmp[threadIdx.x - 1];
    if (threadIdx.x == 1023) bsum[blockIdx.x] = tmp[1023];
}

// Exclusive scan of chunk totals (nb <= 128).
__global__ void k_scan_b(int* __restrict__ bsum, int nb) {
    __shared__ int tmp[128];
    int t = threadIdx.x;
    int v = (t < nb) ? bsum[t] : 0;
    tmp[t] = v;
    __syncthreads();
    for (int off = 1; off < 128; off <<= 1) {
        int u = (t >= off) ? tmp[t - off] : 0;
        __syncthreads();
        tmp[t] += u;
        __syncthreads();
    }
    if (t < nb) bsum[t] = (t == 0) ? 0 : tmp[t - 1];
}

__global__ void k_scan_c(int* __restrict__ rp, const int* __restrict__ bsum,
                         int* __restrict__ cur, int N, int E) {
    int i = blockIdx.x * blockDim.x + threadIdx.x;
    if (i < N) {
        int v = rp[i] + bsum[i >> 10];
        rp[i] = v;
        cur[i] = v;
    } else if (i == N) {
        rp[N] = E;
    }
}

__global__ void k_scatter(const int* __restrict__ src, const int* __restrict__ dst,
                          int* __restrict__ cur, int* __restrict__ srt, int E) {
    int e = blockIdx.x * blockDim.x + threadIdx.x;
    if (e < E) {
        int d = dst[e];
        int pos = atomicAdd(&cur[d], 1);
        srt[pos] = src[e];
    }
}

// t[r][:] = (A[r][:] @ W1) * dinv[r] via bf16 MFMA 16x16x32, f32 out.
// Block: 128 rows; wave w handles rows [w*32, w*32+32): 2 row-groups x 8
// col-groups of 16x16 tiles, K=128 in 4 steps of 32.
__global__ __launch_bounds__(256) void k_mm_mfma(
    const float* __restrict__ A, const unsigned short* __restrict__ w1p,
    const float* __restrict__ dinv, float* __restrict__ C, int N)
{
    __shared__ unsigned short w1s[16384];   // 32 KB packed bf16 W1
    int tid = threadIdx.x;
    {
        const uint4* s = (const uint4*)w1p;
        uint4* d = (uint4*)w1s;
#pragma unroll
        for (int i = 0; i < 8; ++i) d[tid + i * 256] = s[tid + i * 256];
    }
    __syncthreads();

    int w = tid >> 6, lane = tid & 63;
    int m = lane & 15, quad = lane >> 4;
    int r0 = blockIdx.x * 128 + w * 32;

    f32x4 acc[2][8];
#pragma unroll
    for (int rg = 0; rg < 2; ++rg)
#pragma unroll
        for (int cg = 0; cg < 8; ++cg) {
            f32x4 z = {0.0f, 0.0f, 0.0f, 0.0f};
            acc[rg][cg] = z;
        }

#pragma unroll
    for (int ks = 0; ks < 4; ++ks) {
        int k0 = ks * 32 + quad * 8;
        short8 a[2];
#pragma unroll
        for (int rg = 0; rg < 2; ++rg) {
            int r = r0 + rg * 16 + m;
            if (r > N - 1) r = N - 1;
            const float* ap = A + (size_t)r * 128 + k0;
            float4 v0 = *(const float4*)ap;
            float4 v1 = *(const float4*)(ap + 4);
            short8 av;
            av[0] = (short)bf16r(v0.x); av[1] = (short)bf16r(v0.y);
            av[2] = (short)bf16r(v0.z); av[3] = (short)bf16r(v0.w);
            av[4] = (short)bf16r(v1.x); av[5] = (short)bf16r(v1.y);
            av[6] = (short)bf16r(v1.z); av[7] = (short)bf16r(v1.w);
            a[rg] = av;
        }
        int kc = ks * 4 + quad;
#pragma unroll
        for (int cg = 0; cg < 8; ++cg) {
            const short8* bp = (const short8*)&w1s[((size_t)kc * 128 + cg * 16 + m) * 8];
            short8 b = *bp;
            acc[0][cg] = __builtin_amdgcn_mfma_f32_16x16x32_bf16(a[0], b, acc[0][cg], 0, 0, 0);
            acc[1][cg] = __builtin_amdgcn_mfma_f32_16x16x32_bf16(a[1], b, acc[1][cg], 0, 0, 0);
        }
    }

    // C/D layout: col = lane&15, row = quad*4 + reg  [guide §3, m89-verified]
#pragma unroll
    for (int rg = 0; rg < 2; ++rg) {
        int rbase = r0 + rg * 16 + quad * 4;
#pragma unroll
        for (int reg = 0; reg < 4; ++reg) {
            int r = rbase + reg;
            if (r < N) {
                float s = dinv[r];
#pragma unroll
                for (int cg = 0; cg < 8; ++cg)
                    C[(size_t)r * 128 + cg * 16 + m] = acc[rg][cg][reg] * s;
            }
        }
    }
}

// Edge accumulation with 8 gathers in flight (R2 best config): sum over
// in-edges (pre-scaled rows) + self row, float2 per lane.
__device__ __forceinline__ float2 edge_accum(
    const float* __restrict__ t, const int* __restrict__ srt,
    int s0, int s1, int node, int lane)
{
    float2 a0 = {0,0}, a1 = {0,0}, a2 = {0,0}, a3 = {0,0};
    int e = s0;
    int fo = lane * 2;
    while (e + 8 <= s1) {
        int idx[8];
#pragma unroll
        for (int j = 0; j < 8; ++j) idx[j] = srt[e + j];
        float2 v[8];
#pragma unroll
        for (int j = 0; j < 8; ++j)
            v[j] = *(const float2*)(t + (size_t)idx[j] * 128 + fo);
        a0.x += v[0].x; a0.y += v[0].y;  a1.x += v[1].x; a1.y += v[1].y;
        a2.x += v[2].x; a2.y += v[2].y;  a3.x += v[3].x; a3.y += v[3].y;
        a0.x += v[4].x; a0.y += v[4].y;  a1.x += v[5].x; a1.y += v[5].y;
        a2.x += v[6].x; a2.y += v[6].y;  a3.x += v[7].x; a3.y += v[7].y;
        e += 8;
    }
    if (e + 4 <= s1) {
        int idx[4];
#pragma unroll
        for (int j = 0; j < 4; ++j) idx[j] = srt[e + j];
        float2 v[4];
#pragma unroll
        for (int j = 0; j < 4; ++j)
            v[j] = *(const float2*)(t + (size_t)idx[j] * 128 + fo);
        a0.x += v[0].x; a0.y += v[0].y;  a1.x += v[1].x; a1.y += v[1].y;
        a2.x += v[2].x; a2.y += v[2].y;  a3.x += v[3].x; a3.y += v[3].y;
        e += 4;
    }
    for (; e < s1; ++e) {
        int s = srt[e];
        float2 v = *(const float2*)(t + (size_t)s * 128 + fo);
        a0.x += v.x; a0.y += v.y;
    }
    float2 vs = *(const float2*)(t + (size_t)node * 128 + fo);  // self loop
    float2 acc;
    acc.x = (a0.x + a1.x) + (a2.x + a3.x) + vs.x;
    acc.y = (a0.y + a1.y) + (a2.y + a3.y) + vs.y;
    return acc;
}

// One wave per node: h1 = relu((sum_in t + t[self])*dinv + b1), then the
// collapsed layer-2 projection q[node] = dinv * (h1 . w2l). Only q is stored.
__global__ __launch_bounds__(256) void k_agg1(
    const float* __restrict__ t, const float* __restrict__ dinv,
    const int* __restrict__ rp, const int* __restrict__ srt,
    const float* __restrict__ b1, const float* __restrict__ w2l,
    float* __restrict__ q, int N)
{
    int wave = threadIdx.x >> 6;
    int lane = threadIdx.x & 63;
    int node = blockIdx.x * 4 + wave;
    if (node >= N) return;
    int s0 = rp[node], s1 = rp[node + 1];
    float2 acc = edge_accum(t, srt, s0, s1, node, lane);
    float di = dinv[node];
    float2 bb = *(const float2*)(b1 + lane * 2);
    float2 ww = *(const float2*)(w2l + lane * 2);
    float hx = fmaxf(fmaf(acc.x, di, bb.x), 0.0f);
    float hy = fmaxf(fmaf(acc.y, di, bb.y), 0.0f);
    float p = hx * ww.x + hy * ww.y;
#pragma unroll
    for (int off = 32; off > 0; off >>= 1) p += __shfl_down(p, off);
    if (lane == 0) q[node] = p * di;
}

// Collapsed layer-2 aggregation + pooling: one THREAD per node over the
// scalar q table (400 KB, L2-resident). p[v] = dinv[v]*(sum_in q + q[v]).
__global__ __launch_bounds__(256) void k_agg2(
    const float* __restrict__ q, const float* __restrict__ dinv,
    const int* __restrict__ rp, const int* __restrict__ srt,
    const int* __restrict__ batch, float* __restrict__ gsum,
    int* __restrict__ gcnt, int N)
{
    int i = blockIdx.x * blockDim.x + threadIdx.x;
    if (i >= N) return;
    int s0 = rp[i], s1 = rp[i + 1];
    float a0 = 0.0f, a1 = 0.0f, a2 = 0.0f, a3 = 0.0f;
    int e = s0;
    for (; e + 4 <= s1; e += 4) {
        a0 += q[srt[e]];
        a1 += q[srt[e + 1]];
        a2 += q[srt[e + 2]];
        a3 += q[srt[e + 3]];
    }
    for (; e < s1; ++e) a0 += q[srt[e]];
    float p = dinv[i] * ((a0 + a1) + (a2 + a3) + q[i]);
    atomicAdd(&gsum[batch[i]], p);
    atomicAdd(&gcnt[batch[i]], 1);
}

// out[g] = gsum/cnt + b2.Wl + bl   (b2.Wl constant across nodes/graphs)
__global__ void k_final(const float* __restrict__ gsum, const int* __restrict__ gcnt,
                        const float* __restrict__ b2, const float* __restrict__ Wl,
                        const float* __restrict__ bl, float* __restrict__ out, int G) {
    int g = blockIdx.x * blockDim.x + threadIdx.x;
    if (g < G) {
        float c = 0.0f;
        for (int j = 0; j < 128; ++j) c = fmaf(b2[j], Wl[j], c);
        out[g] = gsum[g] / fmaxf((float)gcnt[g], 1.0f) + c + bl[0];
    }
}

extern "C" void kernel_launch(void* const* d_in, const int* in_sizes, int n_in,
                              void* d_out, int out_size, void* d_ws, size_t ws_size,
                              hipStream_t stream)
{
    const float* x  = (const float*)d_in[0];
    const int*   ei = (const int*)d_in[1];
    // d_in[2] = edge_attr: unused by the reference
    const int*   batch = (const int*)d_in[3];
    const float* W1 = (const float*)d_in[4];
    const float* b1 = (const float*)d_in[5];
    const float* W2 = (const float*)d_in[6];
    const float* b2 = (const float*)d_in[7];
    const float* Wl = (const float*)d_in[8];
    const float* bl = (const float*)d_in[9];

    int N = in_sizes[0] / 128;
    int E = in_sizes[1] / 2;
    const int* src = ei;
    const int* dst = ei + E;

    char* ws = (char*)d_ws;
    size_t off = 0;
    auto alloc = [&](size_t bytes) -> void* {
        void* p = ws + off;
        off = (off + bytes + 255) & ~(size_t)255;
        return p;
    };
    float* t    = (float*)alloc((size_t)N * 128 * 4);   // (x@W1)*dinv, f32
    float* q    = (float*)alloc((size_t)N * 4);         // collapsed layer-2 scalars
    int*   srt  = (int*)alloc((size_t)E * 4);
    int*   cnt  = (int*)alloc((size_t)N * 4);
    float* dinv = (float*)alloc((size_t)N * 4);
    int*   rp   = (int*)alloc((size_t)(N + 1) * 4);
    int*   cur  = (int*)alloc((size_t)N * 4);
    int*   bsum = (int*)alloc(1024 * 4);
    float* gsum = (float*)alloc(512 * 4);
    int*   gcnt = (int*)alloc(512 * 4);
    float* w2l  = (float*)alloc(128 * 4);
    unsigned short* w1p = (unsigned short*)alloc(16384 * 2);
    (void)ws_size;

    hipMemsetAsync(cnt, 0, (size_t)N * 4, stream);
    hipMemsetAsync(gsum, 0, 512 * 4, stream);
    hipMemsetAsync(gcnt, 0, 512 * 4, stream);

    int eb = (E + 255) / 256;
    int nb = (N + 255) / 256;
    k_count<<<eb, 256, 0, stream>>>(dst, cnt, E);
    k_dinv<<<nb, 256, 0, stream>>>(cnt, dinv, N);
    k_w2l<<<1, 128, 0, stream>>>(W2, Wl, w2l);
    k_w1pack<<<64, 256, 0, stream>>>(W1, w1p);
    int nchunk = (N + 1023) / 1024;   // 98 <= 128 (k_scan_b capacity)
    k_scan_a<<<nchunk, 1024, 0, stream>>>(cnt, rp, bsum, N);
    k_scan_b<<<1, 128, 0, stream>>>(bsum, nchunk);
    k_scan_c<<<(N + 256) / 256, 256, 0, stream>>>(rp, bsum, cur, N, E);
    k_scatter<<<eb, 256, 0, stream>>>(src, dst, cur, srt, E);

    int mmb = (N + 127) / 128;
    k_mm_mfma<<<mmb, 256, 0, stream>>>(x, w1p, dinv, t, N);
    k_agg1<<<(N + 3) / 4, 256, 0, stream>>>(t, dinv, rp, srt, b1, w2l, q, N);
    k_agg2<<<nb, 256, 0, stream>>>(q, dinv, rp, srt, batch, gsum, gcnt, N);
    k_final<<<2, 256, 0, stream>>>(gsum, gcnt, b2, Wl, bl, (float*)d_out, 512);
}